// Round 4
// baseline (103.506 us; speedup 1.0000x reference)
//
#include <hip/hip_runtime.h>

#define N_NODES 512
#define C_CH    128
#define D_DIM   16
#define S_SPEC  10

typedef _Float16 h8 __attribute__((ext_vector_type(8)));
typedef float f32x4 __attribute__((ext_vector_type(4)));

// ---- K layout: 39 tiles of 32 slots = 8 quads/tile. Quad = (a,b) run x 4 consecutive j.
// Q 0..259: order-3 quads; 260..263 pad; 264..303: order-2; 304..307: order-1; 308..311 pad.
#define KT 39
#define NT 11

__device__ h8  g_Bf[KT * NT * 64];   // B pre-swizzled to MFMA B-frag order [kt][nt][lane]
__device__ int2 g_runtab[KT * 4];    // per (kt, lane-group): 2 packed quads

struct QI { int type, p1, p2, jp; };  // type3: p1=a,p2=b; type2: p1=a; jp = pair idx (j=2*jp..)

__device__ QI quad_info(int Q) {
  if (Q < 260) {
    int q = Q;
    for (int a = 0; a < 16; ++a)
      for (int b = a; b < 16; ++b) {
        int nq = (16 - (b & ~1) + 3) >> 2;
        if (q < nq) { QI r = {3, a, b, ((b & ~1) >> 1) + 2 * q}; return r; }
        q -= nq;
      }
  } else if (Q >= 264 && Q < 304) {
    int q = Q - 264;
    for (int a = 0; a < 16; ++a) {
      int nq = (16 - (a & ~1) + 3) >> 2;
      if (q < nq) { QI r = {2, a, 16, ((a & ~1) >> 1) + 2 * q}; return r; }
      q -= nq;
    }
  } else if (Q >= 304 && Q < 308) {
    QI r = {1, 16, 16, 2 * (Q - 304)}; return r;
  }
  QI r = {0, 16, 16, 8}; return r;  // pad: reads rows 16/17 (finite), B row = 0
}

__device__ __forceinline__ void o_to_iri(int o, int& ir, int& i) {
  if (o >= 9)      { ir = 3; i = o - 9; }
  else if (o >= 4) { ir = 2; i = o - 4; }
  else if (o >= 1) { ir = 1; i = o - 1; }
  else             { ir = 0; i = 0; }
}

// ---------------- build kernels ----------------

__global__ void build_runtab() {
  int e = threadIdx.x;
  if (e >= KT * 4) return;
  QI q0 = quad_info(2 * e), q1 = quad_info(2 * e + 1);
  int2 r;
  r.x = q0.p1 | (q0.p2 << 5) | (q0.jp << 10);
  r.y = q1.p1 | (q1.p2 << 5) | (q1.jp << 10);
  g_runtab[e] = r;
}

__global__ void build_B(const float* __restrict__ u1_0, const float* __restrict__ u1_1,
                        const float* __restrict__ u1_2, const float* __restrict__ u1_3,
                        const float* __restrict__ u2_0, const float* __restrict__ u2_1,
                        const float* __restrict__ u2_2, const float* __restrict__ u2_3,
                        const float* __restrict__ u3_0, const float* __restrict__ u3_1,
                        const float* __restrict__ u3_2, const float* __restrict__ u3_3) {
  const int kt = blockIdx.x, nt = blockIdx.y;
  // validity of (kt, nt)
  if (kt <= 32)      { if (nt > 6) return; }
  else if (kt <= 37) { if (nt < 7 || nt > 9) return; }
  else               { if (nt != 10) return; }

  const int t = threadIdx.x;
  const int l = t & 63, i = t >> 6;
  const int o = l & 15;
  int ir, ii; o_to_iri(o, ir, ii);
  const int dis[4] = {1, 3, 5, 7};
  const int di = dis[ir];
  const float* u1s[4] = {u1_0, u1_1, u1_2, u1_3};
  const float* u2s[4] = {u2_0, u2_1, u2_2, u2_3};
  const float* u3s[4] = {u3_0, u3_1, u3_2, u3_3};

  const int s  = (l >> 4) * 8 + i;   // k-slot within tile (A-frag layout)
  const int Q  = kt * 8 + (s >> 2);
  const int qi = s & 3;
  QI q = quad_info(Q);

  float val = 0.f;
  if (q.type == 3) {
    int a = q.p1, b = q.p2, j = 2 * q.jp + qi;
    if (j >= b && j < 16) {
      int k3 = nt;
      const float* u = u3s[ir];
      int P[6][3] = {{a,b,j},{a,j,b},{b,a,j},{b,j,a},{j,a,b},{j,b,a}};
      for (int p = 0; p < 6; ++p) {
        bool dup = false;
        for (int r = 0; r < p; ++r)
          if (P[r][0] == P[p][0] && P[r][1] == P[p][1] && P[r][2] == P[p][2]) { dup = true; break; }
        if (!dup)
          val += u[(((P[p][0] * 16 + P[p][1]) * 16 + P[p][2]) * 7 + k3) * di + ii];
      }
    }
  } else if (q.type == 2) {
    int a = q.p1, bb = 2 * q.jp + qi;
    if (bb >= a && bb < 16) {
      int k2 = nt - 7;
      const float* u = u2s[ir];
      val = u[((a * 16 + bb) * 3 + k2) * di + ii];
      if (bb != a) val += u[((bb * 16 + a) * 3 + k2) * di + ii];
    }
  } else if (q.type == 1) {
    int aa = 2 * q.jp + qi;
    val = u1s[ir][aa * di + ii];
  }
  _Float16* bh = (_Float16*)g_Bf;
  bh[((size_t)(kt * NT + nt) * 64 + l) * 8 + i] = (_Float16)val;
}

// ---------------- main MFMA kernel: no A-staging, no main-loop barriers ----------------

__global__ __launch_bounds__(512) void eqp_mm(
    const float* __restrict__ x, const int* __restrict__ specie,
    const float* __restrict__ w1, const float* __restrict__ w2,
    const float* __restrict__ w3, float* __restrict__ ws, int nsp) {
  __shared__ float xTf[20 * 129];   // rows 0..15 = x, 16 = ones, 17..19 = zeros; stride 129
  __shared__ int2 rtab[KT * 4];

  const int t = threadIdx.x;
  const int l = t & 63;
  const int w = t >> 6;
  const int n = blockIdx.x;
  const int ks = blockIdx.y;

  {  // stage x (transposed) + aux rows + runtab
    const int c = t & 127, h = t >> 7;
    const float4 v = *(const float4*)(x + ((size_t)n * C_CH + c) * D_DIM + h * 4);
    xTf[(h * 4 + 0) * 129 + c] = v.x;
    xTf[(h * 4 + 1) * 129 + c] = v.y;
    xTf[(h * 4 + 2) * 129 + c] = v.z;
    xTf[(h * 4 + 3) * 129 + c] = v.w;
    if (t < 128) xTf[16 * 129 + t] = 1.0f;
    else { int idx = t - 128; xTf[(17 + (idx >> 7)) * 129 + (idx & 127)] = 0.f; }
    if (t < KT * 4) rtab[t] = g_runtab[t];
  }
  __syncthreads();

  const int s = specie[n];
  const int g = l >> 4;
  const int ch = w * 16 + (l & 15);     // producer channel = A-frag row this lane feeds

  f32x4 acc[NT];
#pragma unroll
  for (int i = 0; i < NT; ++i) acc[i] = (f32x4){0.f, 0.f, 0.f, 0.f};

  const int kt0 = (nsp == 2 && ks == 1) ? 20 : 0;
  const int kt1 = (nsp == 2 && ks == 0) ? 20 : KT;

#pragma unroll 1
  for (int kt = kt0; kt < kt1; ++kt) {
    const int2 rt = rtab[kt * 4 + g];
    h8 af;
    {
      const int oA = rt.x & 31, oB = (rt.x >> 5) & 31, j2 = (rt.x >> 10) * 2;
      const float xab = xTf[oA * 129 + ch] * xTf[oB * 129 + ch];
      af[0] = (_Float16)(xab * xTf[(j2 + 0) * 129 + ch]);
      af[1] = (_Float16)(xab * xTf[(j2 + 1) * 129 + ch]);
      af[2] = (_Float16)(xab * xTf[(j2 + 2) * 129 + ch]);
      af[3] = (_Float16)(xab * xTf[(j2 + 3) * 129 + ch]);
    }
    {
      const int oA = rt.y & 31, oB = (rt.y >> 5) & 31, j2 = (rt.y >> 10) * 2;
      const float xab = xTf[oA * 129 + ch] * xTf[oB * 129 + ch];
      af[4] = (_Float16)(xab * xTf[(j2 + 0) * 129 + ch]);
      af[5] = (_Float16)(xab * xTf[(j2 + 1) * 129 + ch]);
      af[6] = (_Float16)(xab * xTf[(j2 + 2) * 129 + ch]);
      af[7] = (_Float16)(xab * xTf[(j2 + 3) * 129 + ch]);
    }
    const h8* bp = &g_Bf[(size_t)(kt * NT) * 64 + l];
    if (kt <= 32) {
#pragma unroll
      for (int nt = 0; nt < 7; ++nt)
        acc[nt] = __builtin_amdgcn_mfma_f32_16x16x32_f16(af, bp[nt * 64], acc[nt], 0, 0, 0);
    } else if (kt <= 37) {
#pragma unroll
      for (int nt = 7; nt < 10; ++nt)
        acc[nt] = __builtin_amdgcn_mfma_f32_16x16x32_f16(af, bp[nt * 64], acc[nt], 0, 0, 0);
    } else {
      acc[10] = __builtin_amdgcn_mfma_f32_16x16x32_f16(af, bp[10 * 64], acc[10], 0, 0, 0);
    }
  }

  // ---- fold species weights from C-fragment, write partial red[(ks,n)][o][c] ----
  {
    const int o = l & 15;
    int ir, ii; o_to_iri(o, ir, ii); (void)ii;
    const int cb = w * 16 + g * 4;   // 4 consecutive channel rows (C-frag regs)
    float tot[4] = {0.f, 0.f, 0.f, 0.f};
#pragma unroll
    for (int k = 0; k < 7; ++k) {
      const float4 wv = *(const float4*)(w3 + ((size_t)(ir * S_SPEC + s) * 7 + k) * C_CH + cb);
      tot[0] = fmaf(wv.x, acc[k][0], tot[0]);
      tot[1] = fmaf(wv.y, acc[k][1], tot[1]);
      tot[2] = fmaf(wv.z, acc[k][2], tot[2]);
      tot[3] = fmaf(wv.w, acc[k][3], tot[3]);
    }
#pragma unroll
    for (int k = 0; k < 3; ++k) {
      const float4 wv = *(const float4*)(w2 + ((size_t)(ir * S_SPEC + s) * 3 + k) * C_CH + cb);
      tot[0] = fmaf(wv.x, acc[7 + k][0], tot[0]);
      tot[1] = fmaf(wv.y, acc[7 + k][1], tot[1]);
      tot[2] = fmaf(wv.z, acc[7 + k][2], tot[2]);
      tot[3] = fmaf(wv.w, acc[7 + k][3], tot[3]);
    }
    {
      const float4 wv = *(const float4*)(w1 + (size_t)(ir * S_SPEC + s) * C_CH + cb);
      tot[0] = fmaf(wv.x, acc[10][0], tot[0]);
      tot[1] = fmaf(wv.y, acc[10][1], tot[1]);
      tot[2] = fmaf(wv.z, acc[10][2], tot[2]);
      tot[3] = fmaf(wv.w, acc[10][3], tot[3]);
    }
    float4 st = {tot[0], tot[1], tot[2], tot[3]};
    *(float4*)(ws + (((size_t)ks * N_NODES + n) * 16 + o) * C_CH + cb) = st;
  }
}

// ---------------- epilogue: sum partials + wlin channel mix ----------------

template <int HH>
__device__ __forceinline__ void lin_half(const float* __restrict__ redS,
                                         const float* __restrict__ wlin,
                                         float* __restrict__ out, int n, int f) {
  constexpr int irOfA[16] = {0,1,1,1,2,2,2,2,2,3,3,3,3,3,3,3};
  constexpr int iOfA[16]  = {0,0,1,2,0,1,2,3,4,0,1,2,3,4,5,6};
  constexpr int diA[4]  = {1, 3, 5, 7};
  constexpr int ooff[4] = {0, 128, 512, 1152};
  float res[8];
#pragma unroll
  for (int oo = 0; oo < 8; ++oo) res[oo] = 0.f;
  for (int cc = 0; cc < 128; ++cc) {
    float wv[4];
#pragma unroll
    for (int ir = 0; ir < 4; ++ir) wv[ir] = 0.f;
#pragma unroll
    for (int ir = 0; ir < 4; ++ir) {
      bool need = false;
#pragma unroll
      for (int oo = 0; oo < 8; ++oo) need = need || (irOfA[HH * 8 + oo] == ir);
      if (need) wv[ir] = wlin[((size_t)ir * C_CH + cc) * C_CH + f];
    }
#pragma unroll
    for (int oo = 0; oo < 8; ++oo)
      res[oo] = fmaf(redS[(HH * 8 + oo) * 128 + cc], wv[irOfA[HH * 8 + oo]], res[oo]);
  }
  const float inv = 0.08838834764831845f;  // 1/sqrt(128)
  size_t base = (size_t)n * 2048;
#pragma unroll
  for (int oo = 0; oo < 8; ++oo) {
    int o = HH * 8 + oo;
    out[base + ooff[irOfA[o]] + (size_t)f * diA[irOfA[o]] + iOfA[o]] = res[oo] * inv;
  }
}

__global__ __launch_bounds__(256) void eqp_lin(
    const float* __restrict__ ws, const float* __restrict__ wlin,
    float* __restrict__ out, int nsp) {
  __shared__ float redS[2048];  // [o][c]
  const int t = threadIdx.x;
  const int n = blockIdx.x;
  {
    const float4* p0 = (const float4*)(ws + (size_t)n * 2048);
    float4 a = p0[t], b = p0[t + 256];
    if (nsp == 2) {
      const float4* p1 = (const float4*)(ws + ((size_t)N_NODES + n) * 2048);
      float4 a1 = p1[t], b1 = p1[t + 256];
      a.x += a1.x; a.y += a1.y; a.z += a1.z; a.w += a1.w;
      b.x += b1.x; b.y += b1.y; b.z += b1.z; b.w += b1.w;
    }
    ((float4*)redS)[t] = a;
    ((float4*)redS)[t + 256] = b;
  }
  __syncthreads();
  const int f = t & 127;
  if ((t >> 7) == 0) lin_half<0>(redS, wlin, out, n, f);
  else               lin_half<1>(redS, wlin, out, n, f);
}

// ---------------- launch ----------------

extern "C" void kernel_launch(void* const* d_in, const int* in_sizes, int n_in,
                              void* d_out, int out_size, void* d_ws, size_t ws_size,
                              hipStream_t stream) {
  const float* x      = (const float*)d_in[0];
  const int*   specie = (const int*)d_in[1];

  const float *u1s[4], *u2s[4], *u3s[4];
  if (in_sizes[3] == 768) {  // interleaved dict order: u1_0,u2_0,u3_0,u1_1,...
    for (int i = 0; i < 4; ++i) {
      u1s[i] = (const float*)d_in[2 + 3 * i];
      u2s[i] = (const float*)d_in[3 + 3 * i];
      u3s[i] = (const float*)d_in[4 + 3 * i];
    }
  } else {                   // grouped order: u1_0..u1_3,u2_0..u2_3,u3_0..u3_3
    for (int i = 0; i < 4; ++i) {
      u1s[i] = (const float*)d_in[2 + i];
      u2s[i] = (const float*)d_in[6 + i];
      u3s[i] = (const float*)d_in[10 + i];
    }
  }
  const float* w1   = (const float*)d_in[14];
  const float* w2   = (const float*)d_in[15];
  const float* w3   = (const float*)d_in[16];
  const float* wlin = (const float*)d_in[17];
  float* out = (float*)d_out;
  float* ws  = (float*)d_ws;

  const size_t need2 = 2ull * N_NODES * 2048 * sizeof(float);
  const int nsp = (ws_size >= need2) ? 2 : 1;

  build_runtab<<<1, 192, 0, stream>>>();
  build_B<<<dim3(KT, NT), 512, 0, stream>>>(
      u1s[0], u1s[1], u1s[2], u1s[3],
      u2s[0], u2s[1], u2s[2], u2s[3],
      u3s[0], u3s[1], u3s[2], u3s[3]);
  eqp_mm<<<dim3(N_NODES, nsp), 512, 0, stream>>>(x, specie, w1, w2, w3, ws, nsp);
  eqp_lin<<<N_NODES, 256, 0, stream>>>(ws, wlin, out, nsp);
}